// Round 10
// baseline (4473.637 us; speedup 1.0000x reference)
//
#include <hip/hip_runtime.h>
#include <math.h>

// Shapes:
// x:  [8, 2, 2048, 256]
// L1: conv k(8,1) s(4,1) p(2,0): -> [8,48,512,256]; gelu; 1x1 ->96; GLU -> [8,48,512,256]  (y1, ws)
// L2: conv -> [8,96,128,256]; gelu (g2, staged in d_out latent region); 1x1 ->192; GLU -> beforvq (d_out)
// VQ: argmin over 1024 codes of ||f - c||^2, latent = codebook[idx]
//
// d_out layout (fp32): latent [25165824] | indices-as-float [262144] | beforvq [25165824]

#define H1IN 2048
#define H1OUT 512
#define H2IN 512
#define H2OUT 128
#define TT 256
#define NPTS 32768           // 128*256 per batch
#define LAT_ELEMS 25165824   // 8*96*128*256
#define IDX_ELEMS 262144

// ---------------- prep: transpose weights, codebook norms ----------------
__global__ __launch_bounds__(256) void prep_kernel(
    const float* __restrict__ w1, const float* __restrict__ w2,
    const float* __restrict__ w3, const float* __restrict__ w4,
    const float* __restrict__ cb,
    float* __restrict__ w1t, float* __restrict__ w2t,
    float* __restrict__ w3t, float* __restrict__ w4t,
    float* __restrict__ cnorm)
{
    int i = blockIdx.x * 256 + threadIdx.x;
    if (i < 768) {                       // w1t[(ci*8+kh)*48+oc] = w1[(oc*2+ci)*8+kh]
        int oc = i % 48; int r = i / 48;
        w1t[i] = w1[(oc * 2 + (r >> 3)) * 8 + (r & 7)];
    } else if (i < 5376) {               // w2t[c*96+oc] = w2[oc*48+c]
        int j = i - 768;
        int oc = j % 96, c = j / 96;
        w2t[j] = w2[oc * 48 + c];
    } else if (i < 42240) {              // w3t[(ci*8+kh)*96+oc] = w3[(oc*48+ci)*8+kh]
        int j = i - 5376;
        int oc = j % 96; int r = j / 96;
        w3t[j] = w3[(oc * 48 + (r >> 3)) * 8 + (r & 7)];
    } else if (i < 60672) {              // w4t[c*192+oc] = w4[oc*96+c]
        int j = i - 42240;
        int oc = j % 192, c = j / 192;
        w4t[j] = w4[oc * 96 + c];
    } else if (i < 61696) {              // cnorm[k] = sum_d cb[k][d]^2 (fp64 accumulate)
        int k = i - 60672;
        const float* cp = cb + (size_t)k * 96;
        double s = 0.0;
        for (int d = 0; d < 96; d++) s += (double)cp[d] * (double)cp[d];
        cnorm[k] = (float)s;
    }
}

__device__ __forceinline__ float gelu_tanh(float v) {
    float u = 0.7978845608028654f * (v + 0.044715f * v * v * v);
    return 0.5f * v * (1.f + tanhf(u));
}

// ---------------- layer 1 fused: conv + gelu + 1x1 + GLU ----------------
// launch_bounds(256,2): budget ~256 VGPR -> g[48]+z[96] stay in registers.
// Works because g/z are ACCUMULATORS and the weight loads are PROVABLY
// UNIFORM (derived from loop induction vars -> scalar s_load, zero VGPR
// pressure). {accumulator + scalar operand + streamed vector value} is the
// only shape this backend compiles at high VGPR without spill (vq R0-R9).
__global__ __launch_bounds__(256, 2) void henc1_kernel(
    const float* __restrict__ x, const float* __restrict__ w1t,
    const float* __restrict__ b1, const float* __restrict__ w2t,
    const float* __restrict__ b2, float* __restrict__ y1)
{
    __shared__ float gs[48 * 256];
    int bh = blockIdx.x;           // b*512 + ho
    int ho = bh & 511, b = bh >> 9;
    int t = threadIdx.x;

    float g[48];
#pragma unroll
    for (int oc = 0; oc < 48; oc++) g[oc] = b1[oc];

    const float* xb = x + (size_t)b * 2 * H1IN * TT;
    int hbase = ho * 4 - 2;
    for (int ci = 0; ci < 2; ci++) {
        for (int kh = 0; kh < 8; kh++) {
            int hi = hbase + kh;
            float v = (hi >= 0 && hi < H1IN) ? xb[((size_t)ci * H1IN + hi) * TT + t] : 0.f;
            const float* wp = w1t + (ci * 8 + kh) * 48;
#pragma unroll
            for (int oc = 0; oc < 48; oc++) g[oc] = fmaf(v, wp[oc], g[oc]);
        }
    }
#pragma unroll
    for (int oc = 0; oc < 48; oc++) gs[oc * 256 + t] = gelu_tanh(g[oc]);

    float z[96];
#pragma unroll
    for (int oc = 0; oc < 96; oc++) z[oc] = b2[oc];
    for (int c = 0; c < 48; c++) {
        float v = gs[c * 256 + t];
        const float* wp = w2t + c * 96;
#pragma unroll
        for (int oc = 0; oc < 96; oc++) z[oc] = fmaf(v, wp[oc], z[oc]);
    }

    float* yb = y1 + (size_t)b * 48 * H1OUT * TT + (size_t)ho * TT + t;
#pragma unroll
    for (int co = 0; co < 48; co++) {
        float o = z[co] / (1.f + expf(-z[co + 48]));   // a * sigmoid(b)
        yb[(size_t)co * H1OUT * TT] = o;
    }
}

// ---------------- layer 2 conv + gelu ----------------
__global__ __launch_bounds__(256, 2) void conv2a_kernel(
    const float* __restrict__ y1, const float* __restrict__ w3t,
    const float* __restrict__ b3, float* __restrict__ g2)
{
    int bh = blockIdx.x;           // b*128 + ho
    int ho = bh & 127, b = bh >> 7;
    int t = threadIdx.x;

    float g[96];
#pragma unroll
    for (int oc = 0; oc < 96; oc++) g[oc] = b3[oc];

    const float* xb = y1 + (size_t)b * 48 * H2IN * TT;
    int hbase = ho * 4 - 2;
    for (int kh = 0; kh < 8; kh++) {
        int hi = hbase + kh;
        if (hi < 0 || hi >= H2IN) continue;       // wave-uniform branch
        const float* xr = xb + (size_t)hi * TT + t;
        for (int ci = 0; ci < 48; ci++) {
            float v = xr[(size_t)ci * H2IN * TT];
            const float* wp = w3t + (ci * 8 + kh) * 96;
#pragma unroll
            for (int oc = 0; oc < 96; oc++) g[oc] = fmaf(v, wp[oc], g[oc]);
        }
    }

    float* gp = g2 + (size_t)b * 96 * NPTS + (size_t)ho * TT + t;
#pragma unroll
    for (int oc = 0; oc < 96; oc++) gp[(size_t)oc * NPTS] = gelu_tanh(g[oc]);
}

// ---------------- layer 2 rewrite (1x1 -> 192) + GLU ----------------
__global__ __launch_bounds__(256, 2) void rw2b_kernel(
    const float* __restrict__ g2, const float* __restrict__ w4t,
    const float* __restrict__ b4, float* __restrict__ outv)
{
    int i = blockIdx.x * 256 + threadIdx.x;   // 0 .. 262143
    int b = i >> 15, p = i & 32767;
    const float* gp = g2 + (size_t)b * 96 * NPTS + p;
    float* op = outv + (size_t)b * 96 * NPTS + p;

    for (int half = 0; half < 2; half++) {
        float za[48], zb[48];
#pragma unroll
        for (int j = 0; j < 48; j++) {
            za[j] = b4[half * 48 + j];
            zb[j] = b4[96 + half * 48 + j];
        }
        for (int c = 0; c < 96; c++) {
            float v = gp[(size_t)c * NPTS];
            const float* wp = w4t + c * 192;
#pragma unroll
            for (int j = 0; j < 48; j++) {
                za[j] = fmaf(v, wp[half * 48 + j], za[j]);
                zb[j] = fmaf(v, wp[96 + half * 48 + j], zb[j]);
            }
        }
#pragma unroll
        for (int j = 0; j < 48; j++) {
            float o = za[j] / (1.f + expf(-zb[j]));
            op[(size_t)(half * 48 + j) * NPTS] = o;
        }
    }
}

// ---------------- VQ: distances, argmin, gather ----------------
// R10 = R9 with 2x TLP. R9 post-mortem: spill GONE (VGPR 44, the R3
// signature; scratch traffic zero) but vq ran 1923us vs the 328us FMA
// floor at only 4.3 waves/SIMD (LDS-capped 5 blocks/CU). Cause: the
// scalar codebook stream (12KB s_load per k-tile) cannot be pipelined
// WITHIN a wave -- CDNA scalar loads return out-of-order, so every
// consume needs a full lgkmcnt(0) drain. The stall is per-wave
// structural; only co-resident waves hide it (TLP, Guideline 1/7).
// Change: 512-thread blocks, 8 waves, k split 8 ways (w=tid>>6 via
// readfirstlane stays wave-uniform -> s_load preserved). LDS = fs 24KB
// + mb 8KB = 32KB -> 4 blocks/CU (thread-capped) = 32 waves/CU =
// 8 waves/SIMD. Per-wave work halves (128 codes); merge generalizes to
// 8 waves; all inner-loop code byte-identical to the passing R9.
// Decision rule: vq >= 1400us after this -> scalar serialization binds
// beyond TLP -> R11 goes MFMA (bf16 hi/lo split GEMM + fp64 rescue).
__global__ __launch_bounds__(512, 8) void vq_kernel(
    const float* __restrict__ bq, const float* __restrict__ cb,
    const float* __restrict__ cnorm,
    float* __restrict__ latent, float* __restrict__ idxf)
{
    __shared__ float fs[96 * 64];        // [c][pt]
    __shared__ float mb[8][64][4];       // per-wave {best, bi, best2, bi2}
    int tid = threadIdx.x;
    int pl = tid & 63;
    int w = __builtin_amdgcn_readfirstlane(tid >> 6);  // SGPR: provably uniform, 0..7
    int gp0 = blockIdx.x * 64;           // 4096 blocks; 512/batch -> no straddle
    int b = gp0 >> 15, p0 = gp0 & 32767;
    const float* fb = bq + (size_t)b * 96 * NPTS;

    // ---- stage f-tile: 96 channels x 64 points, coalesced (12/thread) ----
    {
        const float* src = fb + p0 + pl;
#pragma unroll 6
        for (int i = 0; i < 12; i++) {
            int c = w * 12 + i;
            fs[c * 64 + pl] = src[(size_t)c * NPTS];
        }
    }
    __syncthreads();

    const float* fl = fs + pl;           // read fl[d*64]

    float best = 3.402823466e+38f, best2 = 3.402823466e+38f;
    int bi = 0, bi2 = 0;
    int kbase = w * 128;                 // this wave's k-eighth (uniform)

#pragma unroll 1
    for (int kt = 0; kt < 4; kt++) {
        int k0 = kbase + kt * 32;
        float acc[32];
#pragma unroll
        for (int j = 0; j < 32; j++) acc[j] = 0.f;

        const float* cbase = cb + (size_t)k0 * 96;   // uniform -> s_load
#pragma unroll 4
        for (int dq = 0; dq < 24; dq++) {
            float f0 = fl[(4 * dq + 0) * 64];
            float f1 = fl[(4 * dq + 1) * 64];
            float f2 = fl[(4 * dq + 2) * 64];
            float f3 = fl[(4 * dq + 3) * 64];
            const float* cq = cbase + dq * 4;
#pragma unroll
            for (int j = 0; j < 32; j++) {
                acc[j] = fmaf(f0, cq[j * 96 + 0], acc[j]);
                acc[j] = fmaf(f1, cq[j * 96 + 1], acc[j]);
                acc[j] = fmaf(f2, cq[j * 96 + 2], acc[j]);
                acc[j] = fmaf(f3, cq[j * 96 + 3], acc[j]);
            }
        }

#pragma unroll
        for (int j = 0; j < 32; j++) {
            float s = fmaf(-2.f, acc[j], cnorm[k0 + j]);
            if (s < best) {                       // strict < -> first-min within eighth
                best2 = best; bi2 = bi;
                best = s;     bi = k0 + j;
            } else if (s < best2) {
                best2 = s;    bi2 = k0 + j;
            }
        }
    }

    // ---- publish per-eighth top-2, merge across the 8 waves ----
    mb[w][pl][0] = best;  mb[w][pl][1] = (float)bi;   // k<=1023 exact in fp32
    mb[w][pl][2] = best2; mb[w][pl][3] = (float)bi2;
    __syncthreads();

    float bs = 3.402823466e+38f, b2 = 3.402823466e+38f;
    int ib = 0, i2 = 0;
#pragma unroll
    for (int ww = 0; ww < 8; ww++) {
#pragma unroll
        for (int pr = 0; pr < 2; pr++) {
            float s = mb[ww][pl][2 * pr];
            int  k = (int)mb[ww][pl][2 * pr + 1];
            if (s < bs || (s == bs && k < ib)) {  // global first-min tie-break
                b2 = bs; i2 = ib; bs = s; ib = k;
            } else if (s < b2 || (s == b2 && k < i2)) {
                b2 = s;  i2 = k;
            }
        }
    }

    // near-tie rescue: fp64 rescore (cold; all 8 threads of a point compute
    // identically from identical merged state -> identical final ib)
    const float* fpt = fb + p0 + pl;
    if (b2 - bs < 1e-3f * fmaxf(1.0f, fabsf(bs))) {
        const float* c1 = cb + (size_t)ib * 96;
        const float* c2 = cb + (size_t)i2 * 96;
        double s1 = 0.0, s2 = 0.0;
        for (int d = 0; d < 96; d++) {
            double fd = (double)fpt[(size_t)d * NPTS];
            double x1 = (double)c1[d], x2 = (double)c2[d];
            s1 += x1 * (x1 - 2.0 * fd);
            s2 += x2 * (x2 - 2.0 * fd);
        }
        if (s2 < s1 || (s2 == s1 && i2 < ib)) ib = i2;
    }

    if (w == 0) idxf[gp0 + pl] = (float)ib;
    const float* cbest = cb + (size_t)ib * 96 + w * 12;
    float* lp = latent + (size_t)b * 96 * NPTS + p0 + pl;
#pragma unroll
    for (int j = 0; j < 12; j++) {
        lp[(size_t)(w * 12 + j) * NPTS] = cbest[j];
    }
}

extern "C" void kernel_launch(void* const* d_in, const int* in_sizes, int n_in,
                              void* d_out, int out_size, void* d_ws, size_t ws_size,
                              hipStream_t stream) {
    const float* x  = (const float*)d_in[0];
    const float* w1 = (const float*)d_in[1];
    const float* b1 = (const float*)d_in[2];
    const float* w2 = (const float*)d_in[3];
    const float* b2 = (const float*)d_in[4];
    const float* w3 = (const float*)d_in[5];
    const float* b3 = (const float*)d_in[6];
    const float* w4 = (const float*)d_in[7];
    const float* b4 = (const float*)d_in[8];
    const float* cb = (const float*)d_in[9];

    float* ws    = (float*)d_ws;
    float* y1    = ws;                       // 50331648 floats (201 MB)
    float* w1t   = ws + 50331648;            // 768
    float* w2t   = w1t + 768;                // 4608
    float* w3t   = w2t + 4608;               // 36864
    float* w4t   = w3t + 36864;              // 18432
    float* cnorm = w4t + 18432;              // 1024

    float* out    = (float*)d_out;
    float* latent = out;
    float* idxf   = out + LAT_ELEMS;
    float* bq     = out + LAT_ELEMS + IDX_ELEMS;
    float* g2     = latent;   // latent region is dead until vq_kernel; reuse as conv2 scratch

    prep_kernel<<<241, 256, 0, stream>>>(w1, w2, w3, w4, cb, w1t, w2t, w3t, w4t, cnorm);
    henc1_kernel<<<8 * 512, 256, 0, stream>>>(x, w1t, b1, w2t, b2, y1);
    conv2a_kernel<<<8 * 128, 256, 0, stream>>>(y1, w3t, b3, g2);
    rw2b_kernel<<<1024, 256, 0, stream>>>(g2, w4t, b4, bq);
    vq_kernel<<<4096, 512, 0, stream>>>(bq, cb, cnorm, latent, idxf);
}

// Round 11
// 1521.181 us; speedup vs baseline: 2.9409x; 2.9409x over previous
//
#include <hip/hip_runtime.h>
#include <math.h>

// Shapes:
// x:  [8, 2, 2048, 256]
// L1: conv k(8,1) s(4,1) p(2,0): -> [8,48,512,256]; gelu; 1x1 ->96; GLU -> [8,48,512,256]  (y1, ws)
// L2: conv -> [8,96,128,256]; gelu (g2, staged in d_out latent region); 1x1 ->192; GLU -> beforvq (d_out)
// VQ: argmin over 1024 codes of ||f - c||^2, latent = codebook[idx]
//
// d_out layout (fp32): latent [25165824] | indices-as-float [262144] | beforvq [25165824]

#define H1IN 2048
#define H1OUT 512
#define H2IN 512
#define H2OUT 128
#define TT 256
#define NPTS 32768           // 128*256 per batch
#define LAT_ELEMS 25165824   // 8*96*128*256
#define IDX_ELEMS 262144

typedef unsigned int uint;
typedef unsigned short ushort_t;
typedef __attribute__((ext_vector_type(8))) short bf16x8;
typedef __attribute__((ext_vector_type(4))) float f32x4;

// fp32 -> bf16 round-to-nearest-even (finite inputs)
__device__ __forceinline__ ushort_t f2bf(float x) {
    uint u = __float_as_uint(x);
    return (ushort_t)((u + 0x7fffu + ((u >> 16) & 1u)) >> 16);
}
__device__ __forceinline__ float bf2f(ushort_t h) {
    return __uint_as_float((uint)h << 16);
}

// ---------------- prep: transpose weights, codebook norms ----------------
__global__ __launch_bounds__(256) void prep_kernel(
    const float* __restrict__ w1, const float* __restrict__ w2,
    const float* __restrict__ w3, const float* __restrict__ w4,
    const float* __restrict__ cb,
    float* __restrict__ w1t, float* __restrict__ w2t,
    float* __restrict__ w3t, float* __restrict__ w4t,
    float* __restrict__ cnorm)
{
    int i = blockIdx.x * 256 + threadIdx.x;
    if (i < 768) {                       // w1t[(ci*8+kh)*48+oc] = w1[(oc*2+ci)*8+kh]
        int oc = i % 48; int r = i / 48;
        w1t[i] = w1[(oc * 2 + (r >> 3)) * 8 + (r & 7)];
    } else if (i < 5376) {               // w2t[c*96+oc] = w2[oc*48+c]
        int j = i - 768;
        int oc = j % 96, c = j / 96;
        w2t[j] = w2[oc * 48 + c];
    } else if (i < 42240) {              // w3t[(ci*8+kh)*96+oc] = w3[(oc*48+ci)*8+kh]
        int j = i - 5376;
        int oc = j % 96; int r = j / 96;
        w3t[j] = w3[(oc * 48 + (r >> 3)) * 8 + (r & 7)];
    } else if (i < 60672) {              // w4t[c*192+oc] = w4[oc*96+c]
        int j = i - 42240;
        int oc = j % 192, c = j / 192;
        w4t[j] = w4[oc * 96 + c];
    } else if (i < 61696) {              // cnorm[k] = sum_d cb[k][d]^2 (fp64 accumulate)
        int k = i - 60672;
        const float* cp = cb + (size_t)k * 96;
        double s = 0.0;
        for (int d = 0; d < 96; d++) s += (double)cp[d] * (double)cp[d];
        cnorm[k] = (float)s;
    }
}

__device__ __forceinline__ float gelu_tanh(float v) {
    float u = 0.7978845608028654f * (v + 0.044715f * v * v * v);
    return 0.5f * v * (1.f + tanhf(u));
}

// ---------------- layer 1 fused: conv + gelu + 1x1 + GLU ----------------
__global__ __launch_bounds__(256, 2) void henc1_kernel(
    const float* __restrict__ x, const float* __restrict__ w1t,
    const float* __restrict__ b1, const float* __restrict__ w2t,
    const float* __restrict__ b2, float* __restrict__ y1)
{
    __shared__ float gs[48 * 256];
    int bh = blockIdx.x;           // b*512 + ho
    int ho = bh & 511, b = bh >> 9;
    int t = threadIdx.x;

    float g[48];
#pragma unroll
    for (int oc = 0; oc < 48; oc++) g[oc] = b1[oc];

    const float* xb = x + (size_t)b * 2 * H1IN * TT;
    int hbase = ho * 4 - 2;
    for (int ci = 0; ci < 2; ci++) {
        for (int kh = 0; kh < 8; kh++) {
            int hi = hbase + kh;
            float v = (hi >= 0 && hi < H1IN) ? xb[((size_t)ci * H1IN + hi) * TT + t] : 0.f;
            const float* wp = w1t + (ci * 8 + kh) * 48;
#pragma unroll
            for (int oc = 0; oc < 48; oc++) g[oc] = fmaf(v, wp[oc], g[oc]);
        }
    }
#pragma unroll
    for (int oc = 0; oc < 48; oc++) gs[oc * 256 + t] = gelu_tanh(g[oc]);

    float z[96];
#pragma unroll
    for (int oc = 0; oc < 96; oc++) z[oc] = b2[oc];
    for (int c = 0; c < 48; c++) {
        float v = gs[c * 256 + t];
        const float* wp = w2t + c * 96;
#pragma unroll
        for (int oc = 0; oc < 96; oc++) z[oc] = fmaf(v, wp[oc], z[oc]);
    }

    float* yb = y1 + (size_t)b * 48 * H1OUT * TT + (size_t)ho * TT + t;
#pragma unroll
    for (int co = 0; co < 48; co++) {
        float o = z[co] / (1.f + expf(-z[co + 48]));   // a * sigmoid(b)
        yb[(size_t)co * H1OUT * TT] = o;
    }
}

// ---------------- layer 2 conv + gelu ----------------
__global__ __launch_bounds__(256, 2) void conv2a_kernel(
    const float* __restrict__ y1, const float* __restrict__ w3t,
    const float* __restrict__ b3, float* __restrict__ g2)
{
    int bh = blockIdx.x;           // b*128 + ho
    int ho = bh & 127, b = bh >> 7;
    int t = threadIdx.x;

    float g[96];
#pragma unroll
    for (int oc = 0; oc < 96; oc++) g[oc] = b3[oc];

    const float* xb = y1 + (size_t)b * 48 * H2IN * TT;
    int hbase = ho * 4 - 2;
    for (int kh = 0; kh < 8; kh++) {
        int hi = hbase + kh;
        if (hi < 0 || hi >= H2IN) continue;       // wave-uniform branch
        const float* xr = xb + (size_t)hi * TT + t;
        for (int ci = 0; ci < 48; ci++) {
            float v = xr[(size_t)ci * H2IN * TT];
            const float* wp = w3t + (ci * 8 + kh) * 96;
#pragma unroll
            for (int oc = 0; oc < 96; oc++) g[oc] = fmaf(v, wp[oc], g[oc]);
        }
    }

    float* gp = g2 + (size_t)b * 96 * NPTS + (size_t)ho * TT + t;
#pragma unroll
    for (int oc = 0; oc < 96; oc++) gp[(size_t)oc * NPTS] = gelu_tanh(g[oc]);
}

// ---------------- layer 2 rewrite (1x1 -> 192) + GLU + bf16 hi/lo emit ----
// R11: epilogue additionally writes fh/fl (bf16 hi/lo split of the GLU
// output, [n][c] row-major) for the MFMA vq, and the first 98304 threads
// also split the codebook into cbh/cbl. All go into the dead y1 region.
__global__ __launch_bounds__(256, 2) void rw2b_kernel(
    const float* __restrict__ g2, const float* __restrict__ w4t,
    const float* __restrict__ b4, float* __restrict__ outv,
    const float* __restrict__ cb,
    ushort_t* __restrict__ fh, ushort_t* __restrict__ fl,
    ushort_t* __restrict__ cbh, ushort_t* __restrict__ cbl)
{
    int i = blockIdx.x * 256 + threadIdx.x;   // 0 .. 262143
    if (i < 98304) {                          // codebook bf16 hi/lo split
        float xv = cb[i];
        ushort_t h = f2bf(xv);
        cbh[i] = h;
        cbl[i] = f2bf(xv - bf2f(h));
    }

    int b = i >> 15, p = i & 32767;
    const float* gp = g2 + (size_t)b * 96 * NPTS + p;
    float* op = outv + (size_t)b * 96 * NPTS + p;

    for (int half = 0; half < 2; half++) {
        float za[48], zb[48];
#pragma unroll
        for (int j = 0; j < 48; j++) {
            za[j] = b4[half * 48 + j];
            zb[j] = b4[96 + half * 48 + j];
        }
        for (int c = 0; c < 96; c++) {
            float v = gp[(size_t)c * NPTS];
            const float* wp = w4t + c * 192;
#pragma unroll
            for (int j = 0; j < 48; j++) {
                za[j] = fmaf(v, wp[half * 48 + j], za[j]);
                zb[j] = fmaf(v, wp[96 + half * 48 + j], zb[j]);
            }
        }
        uint* fhp = (uint*)(fh + (size_t)i * 96 + half * 48);
        uint* flp = (uint*)(fl + (size_t)i * 96 + half * 48);
#pragma unroll
        for (int q = 0; q < 24; q++) {
            float o0 = za[2 * q]     / (1.f + expf(-zb[2 * q]));
            float o1 = za[2 * q + 1] / (1.f + expf(-zb[2 * q + 1]));
            op[(size_t)(half * 48 + 2 * q)     * NPTS] = o0;
            op[(size_t)(half * 48 + 2 * q + 1) * NPTS] = o1;
            ushort_t h0 = f2bf(o0); ushort_t l0 = f2bf(o0 - bf2f(h0));
            ushort_t h1 = f2bf(o1); ushort_t l1 = f2bf(o1 - bf2f(h1));
            fhp[q] = (uint)h0 | ((uint)h1 << 16);
            flp[q] = (uint)l0 | ((uint)l1 << 16);
        }
    }
}

// ---------------- VQ via MFMA: bf16 hi/lo screen + fp64 top-4 rescore ----
// R11 pivot (pre-committed at R9: vq>=1400us on the VALU path -> MFMA).
// History: the VALU path is compiler-bound at ~1200us best (R0); every
// restructure hit remat/spill/divergence pathologies (R0-R10 journal).
// Design: S = F.C^T as 16x16x32 bf16 MFMA. f=fh+fl, c=ch+cl (bf16 RNE);
// dot ~ fh.ch + fh.cl + fl.ch (9 MFMAs per 16x16 tile, K=96); dropped
// fl.cl <= ~4e-4 abs on scores O(100). MFMA scores only SCREEN: per-lane
// top-4 insertion, 16-lane bitonic butterfly merge -> per-point top-4,
// then fp64 ALWAYS-rescore of all 4 candidates (k-order tie-break) ->
// exact final index (same semantics as R0-R10's rescue, which passed).
// Fragment layouts (guide §3 + m156): D: col=lane&15,row=(lane>>4)*4+reg
// (HW-verified); A: row=lane&15, k=8*(lane>>4)+j; B: col=lane&15, same k.
// Wave = 16 points x all 1024 codes; block = 4 waves; no inter-wave dep
// until the tiny mbuf exchange.
__global__ __launch_bounds__(256, 4) void vqm_kernel(
    const float* __restrict__ bq,
    const ushort_t* __restrict__ fh, const ushort_t* __restrict__ fl,
    const ushort_t* __restrict__ cbh, const ushort_t* __restrict__ cbl,
    const float* __restrict__ cb, const float* __restrict__ cnorm,
    float* __restrict__ latent, float* __restrict__ idxf)
{
    __shared__ float mbuf[4][16][8];     // [wave][point][4 s | 4 k]
    int tid = threadIdx.x;
    int lane = tid & 63;
    int wid = __builtin_amdgcn_readfirstlane(tid >> 6);   // 0..3 (R9 lesson)
    int lrow = lane & 15, lgrp = lane >> 4;
    int gp0 = blockIdx.x * 64;           // 4096 blocks; 512/batch -> no straddle
    int b = gp0 >> 15, p0 = gp0 & 32767;
    int pbase = gp0 + wid * 16;          // wave's 16 global points

    // ---- A fragments: point = pbase+lrow, dims kk*32 + 8*lgrp .. +7 ----
    bf16x8 ah[3], al[3];
    {
        const ushort_t* ph = fh + (size_t)(pbase + lrow) * 96 + 8 * lgrp;
        const ushort_t* pl = fl + (size_t)(pbase + lrow) * 96 + 8 * lgrp;
#pragma unroll
        for (int kk = 0; kk < 3; kk++) {
            ah[kk] = *(const bf16x8*)(ph + kk * 32);
            al[kk] = *(const bf16x8*)(pl + kk * 32);
        }
    }

    float bs[4][4]; int bk[4][4];        // per r: sorted ascending top-4
#pragma unroll
    for (int r = 0; r < 4; r++)
#pragma unroll
        for (int j = 0; j < 4; j++) { bs[r][j] = 3.402823466e+38f; bk[r][j] = 0x7fffffff; }

#pragma unroll 1
    for (int ct = 0; ct < 64; ct++) {
        int code = ct * 16 + lrow;
        const ushort_t* qh = cbh + (size_t)code * 96 + 8 * lgrp;
        const ushort_t* ql = cbl + (size_t)code * 96 + 8 * lgrp;
        bf16x8 bh0 = *(const bf16x8*)(qh);
        bf16x8 bh1 = *(const bf16x8*)(qh + 32);
        bf16x8 bh2 = *(const bf16x8*)(qh + 64);
        bf16x8 bl0 = *(const bf16x8*)(ql);
        bf16x8 bl1 = *(const bf16x8*)(ql + 32);
        bf16x8 bl2 = *(const bf16x8*)(ql + 64);
        float cn = cnorm[code];

        f32x4 acc = {0.f, 0.f, 0.f, 0.f};
        acc = __builtin_amdgcn_mfma_f32_16x16x32_bf16(ah[0], bh0, acc, 0, 0, 0);
        acc = __builtin_amdgcn_mfma_f32_16x16x32_bf16(ah[1], bh1, acc, 0, 0, 0);
        acc = __builtin_amdgcn_mfma_f32_16x16x32_bf16(ah[2], bh2, acc, 0, 0, 0);
        acc = __builtin_amdgcn_mfma_f32_16x16x32_bf16(ah[0], bl0, acc, 0, 0, 0);
        acc = __builtin_amdgcn_mfma_f32_16x16x32_bf16(ah[1], bl1, acc, 0, 0, 0);
        acc = __builtin_amdgcn_mfma_f32_16x16x32_bf16(ah[2], bl2, acc, 0, 0, 0);
        acc = __builtin_amdgcn_mfma_f32_16x16x32_bf16(al[0], bh0, acc, 0, 0, 0);
        acc = __builtin_amdgcn_mfma_f32_16x16x32_bf16(al[1], bh1, acc, 0, 0, 0);
        acc = __builtin_amdgcn_mfma_f32_16x16x32_bf16(al[2], bh2, acc, 0, 0, 0);

#pragma unroll
        for (int r = 0; r < 4; r++) {
            float s = fmaf(-2.f, acc[r], cn);
            if (s < bs[r][3]) {          // codes arrive in ascending k; strict <
                bs[r][3] = s; bk[r][3] = code;
                if (bs[r][3] < bs[r][2]) {
                    float ts = bs[r][2]; bs[r][2] = bs[r][3]; bs[r][3] = ts;
                    int   tk = bk[r][2]; bk[r][2] = bk[r][3]; bk[r][3] = tk;
                    if (bs[r][2] < bs[r][1]) {
                        ts = bs[r][1]; bs[r][1] = bs[r][2]; bs[r][2] = ts;
                        tk = bk[r][1]; bk[r][1] = bk[r][2]; bk[r][2] = tk;
                        if (bs[r][1] < bs[r][0]) {
                            ts = bs[r][0]; bs[r][0] = bs[r][1]; bs[r][1] = ts;
                            tk = bk[r][0]; bk[r][0] = bk[r][1]; bk[r][1] = tk;
                        }
                    }
                }
            }
        }
    }

    // ---- butterfly merge of sorted top-4 across the 16 lanes (per r) ----
    // (s,k) comparator: smaller s wins; tie -> smaller k (global first-min).
#define CSW(si, ki, sj, kj) { bool c_ = (sj < si) || (sj == si && kj < ki); \
        float ls_ = c_ ? sj : si; float hs_ = c_ ? si : sj;                 \
        int   lk_ = c_ ? kj : ki; int   hk_ = c_ ? ki : kj;                 \
        si = ls_; ki = lk_; sj = hs_; kj = hk_; }
#pragma unroll
    for (int m = 1; m <= 8; m <<= 1) {
#pragma unroll
        for (int r = 0; r < 4; r++) {
            float os0 = __shfl_xor(bs[r][0], m), os1 = __shfl_xor(bs[r][1], m);
            float os2 = __shfl_xor(bs[r][2], m), os3 = __shfl_xor(bs[r][3], m);
            int   ok0 = __shfl_xor(bk[r][0], m), ok1 = __shfl_xor(bk[r][1], m);
            int   ok2 = __shfl_xor(bk[r][2], m), ok3 = __shfl_xor(bk[r][3], m);
            // bitonic stage 1: L_i = min(a_i, o_{3-i}) -> lowest 4, bitonic
            bool t0 = (bs[r][0] < os3) || (bs[r][0] == os3 && bk[r][0] < ok3);
            bool t1 = (bs[r][1] < os2) || (bs[r][1] == os2 && bk[r][1] < ok2);
            bool t2 = (bs[r][2] < os1) || (bs[r][2] == os1 && bk[r][2] < ok1);
            bool t3 = (bs[r][3] < os0) || (bs[r][3] == os0 && bk[r][3] < ok0);
            float L0s = t0 ? bs[r][0] : os3;  int L0k = t0 ? bk[r][0] : ok3;
            float L1s = t1 ? bs[r][1] : os2;  int L1k = t1 ? bk[r][1] : ok2;
            float L2s = t2 ? bs[r][2] : os1;  int L2k = t2 ? bk[r][2] : ok1;
            float L3s = t3 ? bs[r][3] : os0;  int L3k = t3 ? bk[r][3] : ok0;
            // bitonic sort-4
            CSW(L0s, L0k, L2s, L2k); CSW(L1s, L1k, L3s, L3k);
            CSW(L0s, L0k, L1s, L1k); CSW(L2s, L2k, L3s, L3k);
            bs[r][0] = L0s; bk[r][0] = L0k; bs[r][1] = L1s; bk[r][1] = L1k;
            bs[r][2] = L2s; bk[r][2] = L2k; bs[r][3] = L3s; bk[r][3] = L3k;
        }
    }
#undef CSW

    if (lrow == 0) {
#pragma unroll
        for (int r = 0; r < 4; r++) {
            int pt = lgrp * 4 + r;
#pragma unroll
            for (int j = 0; j < 4; j++) {
                mbuf[wid][pt][j] = bs[r][j];
                mbuf[wid][pt][4 + j] = (float)bk[r][j];   // k<=1023 exact
            }
        }
    }
    __syncthreads();

    // ---- fp64 rescore of the 4 candidates: lane = (point lrow, cand lgrp) ----
    int p = lrow;
    int kj = (int)mbuf[wid][p][4 + lgrp];
    const float* fpt = bq + (size_t)b * 96 * NPTS + (p0 + wid * 16 + p);
    const float* cj = cb + (size_t)kj * 96;
    double sd = 0.0;
    for (int d = 0; d < 96; d++) {
        double fd = (double)fpt[(size_t)d * NPTS];
        double xv = (double)cj[d];
        sd = fma(xv, xv - 2.0 * fd, sd);
    }
#pragma unroll
    for (int m = 16; m <= 32; m <<= 1) {
        double so = __shfl_xor(sd, m);
        int    ko = __shfl_xor(kj, m);
        if (so < sd || (so == sd && ko < kj)) { sd = so; kj = ko; }
    }
    if (lgrp == 0) idxf[gp0 + wid * 16 + p] = (float)kj;

    // ---- gather: lane writes 24 channels of its point ----
    const float* cbest = cb + (size_t)kj * 96;
    float* lp = latent + (size_t)b * 96 * NPTS + (p0 + wid * 16 + p);
#pragma unroll
    for (int i = 0; i < 24; i++) {
        int c = lgrp * 24 + i;
        lp[(size_t)c * NPTS] = cbest[c];
    }
}

extern "C" void kernel_launch(void* const* d_in, const int* in_sizes, int n_in,
                              void* d_out, int out_size, void* d_ws, size_t ws_size,
                              hipStream_t stream) {
    const float* x  = (const float*)d_in[0];
    const float* w1 = (const float*)d_in[1];
    const float* b1 = (const float*)d_in[2];
    const float* w2 = (const float*)d_in[3];
    const float* b2 = (const float*)d_in[4];
    const float* w3 = (const float*)d_in[5];
    const float* b3 = (const float*)d_in[6];
    const float* w4 = (const float*)d_in[7];
    const float* b4 = (const float*)d_in[8];
    const float* cb = (const float*)d_in[9];

    float* ws    = (float*)d_ws;
    float* y1    = ws;                       // 50331648 floats (201 MB); dead after conv2a
    float* w1t   = ws + 50331648;            // 768
    float* w2t   = w1t + 768;                // 4608
    float* w3t   = w2t + 4608;               // 36864
    float* w4t   = w3t + 36864;              // 18432
    float* cnorm = w4t + 18432;              // 1024

    // bf16 planes live in the dead y1 region (written by rw2b, after conv2a):
    ushort_t* fh  = (ushort_t*)ws;                    // 25165824 bf16 = 12582912 floats
    ushort_t* fl  = (ushort_t*)(ws + 12582912);       // 25165824 bf16
    ushort_t* cbh = (ushort_t*)(ws + 25165824);       // 98304 bf16 = 49152 floats
    ushort_t* cbl = (ushort_t*)(ws + 25165824 + 49152);

    float* out    = (float*)d_out;
    float* latent = out;
    float* idxf   = out + LAT_ELEMS;
    float* bq     = out + LAT_ELEMS + IDX_ELEMS;
    float* g2     = latent;   // latent region dead until vqm; reuse as conv2 scratch

    prep_kernel<<<241, 256, 0, stream>>>(w1, w2, w3, w4, cb, w1t, w2t, w3t, w4t, cnorm);
    henc1_kernel<<<8 * 512, 256, 0, stream>>>(x, w1t, b1, w2t, b2, y1);
    conv2a_kernel<<<8 * 128, 256, 0, stream>>>(y1, w3t, b3, g2);
    rw2b_kernel<<<1024, 256, 0, stream>>>(g2, w4t, b4, bq, cb, fh, fl, cbh, cbl);
    vqm_kernel<<<4096, 256, 0, stream>>>(bq, fh, fl, cbh, cbl, cb, cnorm, latent, idxf);
}

// Round 12
// 1422.547 us; speedup vs baseline: 3.1448x; 1.0693x over previous
//
#include <hip/hip_runtime.h>
#include <math.h>

// Shapes:
// x:  [8, 2, 2048, 256]
// L1: conv k(8,1) s(4,1) p(2,0): -> [8,48,512,256]; gelu; 1x1 ->96; GLU -> [8,48,512,256]  (y1, ws)
// L2: conv -> [8,96,128,256]; gelu (g2, staged in d_out latent region); 1x1 ->192; GLU -> beforvq (d_out)
// VQ: argmin over 1024 codes of ||f - c||^2, latent = codebook[idx]
//
// d_out layout (fp32): latent [25165824] | indices-as-float [262144] | beforvq [25165824]

#define H1IN 2048
#define H1OUT 512
#define H2IN 512
#define H2OUT 128
#define TT 256
#define NPTS 32768           // 128*256 per batch
#define LAT_ELEMS 25165824   // 8*96*128*256
#define IDX_ELEMS 262144

typedef unsigned int uint;
typedef unsigned short ushort_t;
typedef __attribute__((ext_vector_type(8))) short bf16x8;
typedef __attribute__((ext_vector_type(4))) float f32x4;

// fp32 -> bf16 round-to-nearest-even (finite inputs)
__device__ __forceinline__ ushort_t f2bf(float x) {
    uint u = __float_as_uint(x);
    return (ushort_t)((u + 0x7fffu + ((u >> 16) & 1u)) >> 16);
}
__device__ __forceinline__ float bf2f(ushort_t h) {
    return __uint_as_float((uint)h << 16);
}

// ---------------- prep: transpose weights, codebook norms ----------------
__global__ __launch_bounds__(256) void prep_kernel(
    const float* __restrict__ w1, const float* __restrict__ w2,
    const float* __restrict__ w3, const float* __restrict__ w4,
    const float* __restrict__ cb,
    float* __restrict__ w1t, float* __restrict__ w2t,
    float* __restrict__ w3t, float* __restrict__ w4t,
    float* __restrict__ cnorm)
{
    int i = blockIdx.x * 256 + threadIdx.x;
    if (i < 768) {                       // w1t[(ci*8+kh)*48+oc] = w1[(oc*2+ci)*8+kh]
        int oc = i % 48; int r = i / 48;
        w1t[i] = w1[(oc * 2 + (r >> 3)) * 8 + (r & 7)];
    } else if (i < 5376) {               // w2t[c*96+oc] = w2[oc*48+c]
        int j = i - 768;
        int oc = j % 96, c = j / 96;
        w2t[j] = w2[oc * 48 + c];
    } else if (i < 42240) {              // w3t[(ci*8+kh)*96+oc] = w3[(oc*48+ci)*8+kh]
        int j = i - 5376;
        int oc = j % 96; int r = j / 96;
        w3t[j] = w3[(oc * 48 + (r >> 3)) * 8 + (r & 7)];
    } else if (i < 60672) {              // w4t[c*192+oc] = w4[oc*96+c]
        int j = i - 42240;
        int oc = j % 192, c = j / 192;
        w4t[j] = w4[oc * 96 + c];
    } else if (i < 61696) {              // cnorm[k] = sum_d cb[k][d]^2 (fp64 accumulate)
        int k = i - 60672;
        const float* cp = cb + (size_t)k * 96;
        double s = 0.0;
        for (int d = 0; d < 96; d++) s += (double)cp[d] * (double)cp[d];
        cnorm[k] = (float)s;
    }
}

__device__ __forceinline__ float gelu_tanh(float v) {
    float u = 0.7978845608028654f * (v + 0.044715f * v * v * v);
    return 0.5f * v * (1.f + tanhf(u));
}

// ---------------- layer 1 fused: conv + gelu + 1x1 + GLU ----------------
__global__ __launch_bounds__(256, 2) void henc1_kernel(
    const float* __restrict__ x, const float* __restrict__ w1t,
    const float* __restrict__ b1, const float* __restrict__ w2t,
    const float* __restrict__ b2, float* __restrict__ y1)
{
    __shared__ float gs[48 * 256];
    int bh = blockIdx.x;           // b*512 + ho
    int ho = bh & 511, b = bh >> 9;
    int t = threadIdx.x;

    float g[48];
#pragma unroll
    for (int oc = 0; oc < 48; oc++) g[oc] = b1[oc];

    const float* xb = x + (size_t)b * 2 * H1IN * TT;
    int hbase = ho * 4 - 2;
    for (int ci = 0; ci < 2; ci++) {
        for (int kh = 0; kh < 8; kh++) {
            int hi = hbase + kh;
            float v = (hi >= 0 && hi < H1IN) ? xb[((size_t)ci * H1IN + hi) * TT + t] : 0.f;
            const float* wp = w1t + (ci * 8 + kh) * 48;
#pragma unroll
            for (int oc = 0; oc < 48; oc++) g[oc] = fmaf(v, wp[oc], g[oc]);
        }
    }
#pragma unroll
    for (int oc = 0; oc < 48; oc++) gs[oc * 256 + t] = gelu_tanh(g[oc]);

    float z[96];
#pragma unroll
    for (int oc = 0; oc < 96; oc++) z[oc] = b2[oc];
    for (int c = 0; c < 48; c++) {
        float v = gs[c * 256 + t];
        const float* wp = w2t + c * 96;
#pragma unroll
        for (int oc = 0; oc < 96; oc++) z[oc] = fmaf(v, wp[oc], z[oc]);
    }

    float* yb = y1 + (size_t)b * 48 * H1OUT * TT + (size_t)ho * TT + t;
#pragma unroll
    for (int co = 0; co < 48; co++) {
        float o = z[co] / (1.f + expf(-z[co + 48]));   // a * sigmoid(b)
        yb[(size_t)co * H1OUT * TT] = o;
    }
}

// ---------------- layer 2 conv + gelu ----------------
__global__ __launch_bounds__(256, 2) void conv2a_kernel(
    const float* __restrict__ y1, const float* __restrict__ w3t,
    const float* __restrict__ b3, float* __restrict__ g2)
{
    int bh = blockIdx.x;           // b*128 + ho
    int ho = bh & 127, b = bh >> 7;
    int t = threadIdx.x;

    float g[96];
#pragma unroll
    for (int oc = 0; oc < 96; oc++) g[oc] = b3[oc];

    const float* xb = y1 + (size_t)b * 48 * H2IN * TT;
    int hbase = ho * 4 - 2;
    for (int kh = 0; kh < 8; kh++) {
        int hi = hbase + kh;
        if (hi < 0 || hi >= H2IN) continue;       // wave-uniform branch
        const float* xr = xb + (size_t)hi * TT + t;
        for (int ci = 0; ci < 48; ci++) {
            float v = xr[(size_t)ci * H2IN * TT];
            const float* wp = w3t + (ci * 8 + kh) * 96;
#pragma unroll
            for (int oc = 0; oc < 96; oc++) g[oc] = fmaf(v, wp[oc], g[oc]);
        }
    }

    float* gp = g2 + (size_t)b * 96 * NPTS + (size_t)ho * TT + t;
#pragma unroll
    for (int oc = 0; oc < 96; oc++) gp[(size_t)oc * NPTS] = gelu_tanh(g[oc]);
}

// ---------------- layer 2 rewrite (1x1 -> 192) + GLU + bf16 hi/lo emit ----
__global__ __launch_bounds__(256, 2) void rw2b_kernel(
    const float* __restrict__ g2, const float* __restrict__ w4t,
    const float* __restrict__ b4, float* __restrict__ outv,
    const float* __restrict__ cb,
    ushort_t* __restrict__ fh, ushort_t* __restrict__ fl,
    ushort_t* __restrict__ cbh, ushort_t* __restrict__ cbl)
{
    int i = blockIdx.x * 256 + threadIdx.x;   // 0 .. 262143
    if (i < 98304) {                          // codebook bf16 hi/lo split
        float xv = cb[i];
        ushort_t h = f2bf(xv);
        cbh[i] = h;
        cbl[i] = f2bf(xv - bf2f(h));
    }

    int b = i >> 15, p = i & 32767;
    const float* gp = g2 + (size_t)b * 96 * NPTS + p;
    float* op = outv + (size_t)b * 96 * NPTS + p;

    for (int half = 0; half < 2; half++) {
        float za[48], zb[48];
#pragma unroll
        for (int j = 0; j < 48; j++) {
            za[j] = b4[half * 48 + j];
            zb[j] = b4[96 + half * 48 + j];
        }
        for (int c = 0; c < 96; c++) {
            float v = gp[(size_t)c * NPTS];
            const float* wp = w4t + c * 192;
#pragma unroll
            for (int j = 0; j < 48; j++) {
                za[j] = fmaf(v, wp[half * 48 + j], za[j]);
                zb[j] = fmaf(v, wp[96 + half * 48 + j], zb[j]);
            }
        }
        uint* fhp = (uint*)(fh + (size_t)i * 96 + half * 48);
        uint* flp = (uint*)(fl + (size_t)i * 96 + half * 48);
#pragma unroll
        for (int q = 0; q < 24; q++) {
            float o0 = za[2 * q]     / (1.f + expf(-zb[2 * q]));
            float o1 = za[2 * q + 1] / (1.f + expf(-zb[2 * q + 1]));
            op[(size_t)(half * 48 + 2 * q)     * NPTS] = o0;
            op[(size_t)(half * 48 + 2 * q + 1) * NPTS] = o1;
            ushort_t h0 = f2bf(o0); ushort_t l0 = f2bf(o0 - bf2f(h0));
            ushort_t h1 = f2bf(o1); ushort_t l1 = f2bf(o1 - bf2f(h1));
            fhp[q] = (uint)h0 | ((uint)h1 << 16);
            flp[q] = (uint)l0 | ((uint)l1 << 16);
        }
    }
}

// ---------------- VQ via MFMA: bf16 hi/lo screen + fp64 top-4 rescore ----
// R12 = R11 (PASSED, 548us) + 1-deep software pipeline on the ct loop.
// R11 counters: MfmaUtil 11.7% (MFMA-busy ~64us), VALUBusy 38%, HBM 4.8%
// -> ~50% of cycles idle = L2 latency on the 6 B-fragment loads per ct
// (unroll-1 blocked cross-iteration pipelining; 4 waves/SIMD too few to
// cover ~300cy L2 latency). Fix: prefetch ct+1's fragments + cnorm into a
// second register set while MFMAing ct (Guideline 7); pointer-bump
// addressing. +28 VGPR (~120 live) -> launch_bounds(256,3) (cap 170) so a
// spill is structurally impossible (R7 lesson: spill = 10-70x disaster,
// 1 wave less = 1.3x). Screen/merge/rescue/gather byte-identical to R11.
// Guard: WRITE_SIZE must stay ~99MB (spill watch); vqm >=480us -> latency
// wasn't binding -> R13 goes LDS-shared codebook or top-2 screen.
__global__ __launch_bounds__(256, 3) void vqm_kernel(
    const float* __restrict__ bq,
    const ushort_t* __restrict__ fh, const ushort_t* __restrict__ fl,
    const ushort_t* __restrict__ cbh, const ushort_t* __restrict__ cbl,
    const float* __restrict__ cb, const float* __restrict__ cnorm,
    float* __restrict__ latent, float* __restrict__ idxf)
{
    __shared__ float mbuf[4][16][8];     // [wave][point][4 s | 4 k]
    int tid = threadIdx.x;
    int lane = tid & 63;
    int wid = __builtin_amdgcn_readfirstlane(tid >> 6);   // 0..3 (R9 lesson)
    int lrow = lane & 15, lgrp = lane >> 4;
    int gp0 = blockIdx.x * 64;           // 4096 blocks; 512/batch -> no straddle
    int b = gp0 >> 15, p0 = gp0 & 32767;
    int pbase = gp0 + wid * 16;          // wave's 16 global points

    // ---- A fragments: point = pbase+lrow, dims kk*32 + 8*lgrp .. +7 ----
    bf16x8 ah[3], al[3];
    {
        const ushort_t* ph = fh + (size_t)(pbase + lrow) * 96 + 8 * lgrp;
        const ushort_t* pl = fl + (size_t)(pbase + lrow) * 96 + 8 * lgrp;
#pragma unroll
        for (int kk = 0; kk < 3; kk++) {
            ah[kk] = *(const bf16x8*)(ph + kk * 32);
            al[kk] = *(const bf16x8*)(pl + kk * 32);
        }
    }

    float bs[4][4]; int bk[4][4];        // per r: sorted ascending top-4
#pragma unroll
    for (int r = 0; r < 4; r++)
#pragma unroll
        for (int j = 0; j < 4; j++) { bs[r][j] = 3.402823466e+38f; bk[r][j] = 0x7fffffff; }

    // ---- pipelined ct loop: prefetch ct+1 while MFMAing ct ----
    const ushort_t* qh = cbh + (size_t)lrow * 96 + 8 * lgrp;
    const ushort_t* ql = cbl + (size_t)lrow * 96 + 8 * lgrp;
    const float* cnp = cnorm + lrow;

    bf16x8 nbh0 = *(const bf16x8*)(qh);
    bf16x8 nbh1 = *(const bf16x8*)(qh + 32);
    bf16x8 nbh2 = *(const bf16x8*)(qh + 64);
    bf16x8 nbl0 = *(const bf16x8*)(ql);
    bf16x8 nbl1 = *(const bf16x8*)(ql + 32);
    bf16x8 nbl2 = *(const bf16x8*)(ql + 64);
    float ncn = *cnp;

#pragma unroll 1
    for (int ct = 0; ct < 64; ct++) {
        bf16x8 bh0 = nbh0, bh1 = nbh1, bh2 = nbh2;
        bf16x8 bl0 = nbl0, bl1 = nbl1, bl2 = nbl2;
        float cn = ncn;
        int code = ct * 16 + lrow;

        if (ct < 63) {                   // issue next tile's loads early
            qh += 16 * 96; ql += 16 * 96; cnp += 16;
            nbh0 = *(const bf16x8*)(qh);
            nbh1 = *(const bf16x8*)(qh + 32);
            nbh2 = *(const bf16x8*)(qh + 64);
            nbl0 = *(const bf16x8*)(ql);
            nbl1 = *(const bf16x8*)(ql + 32);
            nbl2 = *(const bf16x8*)(ql + 64);
            ncn = *cnp;
        }

        f32x4 acc = {0.f, 0.f, 0.f, 0.f};
        acc = __builtin_amdgcn_mfma_f32_16x16x32_bf16(ah[0], bh0, acc, 0, 0, 0);
        acc = __builtin_amdgcn_mfma_f32_16x16x32_bf16(ah[1], bh1, acc, 0, 0, 0);
        acc = __builtin_amdgcn_mfma_f32_16x16x32_bf16(ah[2], bh2, acc, 0, 0, 0);
        acc = __builtin_amdgcn_mfma_f32_16x16x32_bf16(ah[0], bl0, acc, 0, 0, 0);
        acc = __builtin_amdgcn_mfma_f32_16x16x32_bf16(ah[1], bl1, acc, 0, 0, 0);
        acc = __builtin_amdgcn_mfma_f32_16x16x32_bf16(ah[2], bl2, acc, 0, 0, 0);
        acc = __builtin_amdgcn_mfma_f32_16x16x32_bf16(al[0], bh0, acc, 0, 0, 0);
        acc = __builtin_amdgcn_mfma_f32_16x16x32_bf16(al[1], bh1, acc, 0, 0, 0);
        acc = __builtin_amdgcn_mfma_f32_16x16x32_bf16(al[2], bh2, acc, 0, 0, 0);

#pragma unroll
        for (int r = 0; r < 4; r++) {
            float s = fmaf(-2.f, acc[r], cn);
            if (s < bs[r][3]) {          // codes arrive in ascending k; strict <
                bs[r][3] = s; bk[r][3] = code;
                if (bs[r][3] < bs[r][2]) {
                    float ts = bs[r][2]; bs[r][2] = bs[r][3]; bs[r][3] = ts;
                    int   tk = bk[r][2]; bk[r][2] = bk[r][3]; bk[r][3] = tk;
                    if (bs[r][2] < bs[r][1]) {
                        ts = bs[r][1]; bs[r][1] = bs[r][2]; bs[r][2] = ts;
                        tk = bk[r][1]; bk[r][1] = bk[r][2]; bk[r][2] = tk;
                        if (bs[r][1] < bs[r][0]) {
                            ts = bs[r][0]; bs[r][0] = bs[r][1]; bs[r][1] = ts;
                            tk = bk[r][0]; bk[r][0] = bk[r][1]; bk[r][1] = tk;
                        }
                    }
                }
            }
        }
    }

    // ---- butterfly merge of sorted top-4 across the 16 lanes (per r) ----
    // (s,k) comparator: smaller s wins; tie -> smaller k (global first-min).
#define CSW(si, ki, sj, kj) { bool c_ = (sj < si) || (sj == si && kj < ki); \
        float ls_ = c_ ? sj : si; float hs_ = c_ ? si : sj;                 \
        int   lk_ = c_ ? kj : ki; int   hk_ = c_ ? ki : kj;                 \
        si = ls_; ki = lk_; sj = hs_; kj = hk_; }
#pragma unroll
    for (int m = 1; m <= 8; m <<= 1) {
#pragma unroll
        for (int r = 0; r < 4; r++) {
            float os0 = __shfl_xor(bs[r][0], m), os1 = __shfl_xor(bs[r][1], m);
            float os2 = __shfl_xor(bs[r][2], m), os3 = __shfl_xor(bs[r][3], m);
            int   ok0 = __shfl_xor(bk[r][0], m), ok1 = __shfl_xor(bk[r][1], m);
            int   ok2 = __shfl_xor(bk[r][2], m), ok3 = __shfl_xor(bk[r][3], m);
            // bitonic stage 1: L_i = min(a_i, o_{3-i}) -> lowest 4, bitonic
            bool t0 = (bs[r][0] < os3) || (bs[r][0] == os3 && bk[r][0] < ok3);
            bool t1 = (bs[r][1] < os2) || (bs[r][1] == os2 && bk[r][1] < ok2);
            bool t2 = (bs[r][2] < os1) || (bs[r][2] == os1 && bk[r][2] < ok1);
            bool t3 = (bs[r][3] < os0) || (bs[r][3] == os0 && bk[r][3] < ok0);
            float L0s = t0 ? bs[r][0] : os3;  int L0k = t0 ? bk[r][0] : ok3;
            float L1s = t1 ? bs[r][1] : os2;  int L1k = t1 ? bk[r][1] : ok2;
            float L2s = t2 ? bs[r][2] : os1;  int L2k = t2 ? bk[r][2] : ok1;
            float L3s = t3 ? bs[r][3] : os0;  int L3k = t3 ? bk[r][3] : ok0;
            // bitonic sort-4
            CSW(L0s, L0k, L2s, L2k); CSW(L1s, L1k, L3s, L3k);
            CSW(L0s, L0k, L1s, L1k); CSW(L2s, L2k, L3s, L3k);
            bs[r][0] = L0s; bk[r][0] = L0k; bs[r][1] = L1s; bk[r][1] = L1k;
            bs[r][2] = L2s; bk[r][2] = L2k; bs[r][3] = L3s; bk[r][3] = L3k;
        }
    }
#undef CSW

    if (lrow == 0) {
#pragma unroll
        for (int r = 0; r < 4; r++) {
            int pt = lgrp * 4 + r;
#pragma unroll
            for (int j = 0; j < 4; j++) {
                mbuf[wid][pt][j] = bs[r][j];
                mbuf[wid][pt][4 + j] = (float)bk[r][j];   // k<=1023 exact
            }
        }
    }
    __syncthreads();

    // ---- fp64 rescore of the 4 candidates: lane = (point lrow, cand lgrp) ----
    int p = lrow;
    int kj = (int)mbuf[wid][p][4 + lgrp];
    const float* fpt = bq + (size_t)b * 96 * NPTS + (p0 + wid * 16 + p);
    const float* cj = cb + (size_t)kj * 96;
    double sd = 0.0;
    for (int d = 0; d < 96; d++) {
        double fd = (double)fpt[(size_t)d * NPTS];
        double xv = (double)cj[d];
        sd = fma(xv, xv - 2.0 * fd, sd);
    }
#pragma unroll
    for (int m = 16; m <= 32; m <<= 1) {
        double so = __shfl_xor(sd, m);
        int    ko = __shfl_xor(kj, m);
        if (so < sd || (so == sd && ko < kj)) { sd = so; kj = ko; }
    }
    if (lgrp == 0) idxf[gp0 + wid * 16 + p] = (float)kj;

    // ---- gather: lane writes 24 channels of its point ----
    const float* cbest = cb + (size_t)kj * 96;
    float* lp = latent + (size_t)b * 96 * NPTS + (p0 + wid * 16 + p);
#pragma unroll
    for (int i = 0; i < 24; i++) {
        int c = lgrp * 24 + i;
        lp[(size_t)c * NPTS] = cbest[c];
    }
}

extern "C" void kernel_launch(void* const* d_in, const int* in_sizes, int n_in,
                              void* d_out, int out_size, void* d_ws, size_t ws_size,
                              hipStream_t stream) {
    const float* x  = (const float*)d_in[0];
    const float* w1 = (const float*)d_in[1];
    const float* b1 = (const float*)d_in[2];
    const float* w2 = (const float*)d_in[3];
    const float* b2 = (const float*)d_in[4];
    const float* w3 = (const float*)d_in[5];
    const float* b3 = (const float*)d_in[6];
    const float* w4 = (const float*)d_in[7];
    const float* b4 = (const float*)d_in[8];
    const float* cb = (const float*)d_in[9];

    float* ws    = (float*)d_ws;
    float* y1    = ws;                       // 50331648 floats (201 MB); dead after conv2a
    float* w1t   = ws + 50331648;            // 768
    float* w2t   = w1t + 768;                // 4608
    float* w3t   = w2t + 4608;               // 36864
    float* w4t   = w3t + 36864;              // 18432
    float* cnorm = w4t + 18432;              // 1024

    // bf16 planes live in the dead y1 region (written by rw2b, after conv2a):
    ushort_t* fh  = (ushort_t*)ws;                    // 25165824 bf16 = 12582912 floats
    ushort_t* fl  = (ushort_t*)(ws + 12582912);       // 25165824 bf16
    ushort_t* cbh = (ushort_t*)(ws + 25165824);       // 98304 bf16 = 49152 floats
    ushort_t* cbl = (ushort_t*)(ws + 25165824 + 49152);

    float* out    = (float*)d_out;
    float* latent = out;
    float* idxf   = out + LAT_ELEMS;
    float* bq     = out + LAT_ELEMS + IDX_ELEMS;
    float* g2     = latent;   // latent region dead until vqm; reuse as conv2 scratch

    prep_kernel<<<241, 256, 0, stream>>>(w1, w2, w3, w4, cb, w1t, w2t, w3t, w4t, cnorm);
    henc1_kernel<<<8 * 512, 256, 0, stream>>>(x, w1t, b1, w2t, b2, y1);
    conv2a_kernel<<<8 * 128, 256, 0, stream>>>(y1, w3t, b3, g2);
    rw2b_kernel<<<1024, 256, 0, stream>>>(g2, w4t, b4, bq, cb, fh, fl, cbh, cbl);
    vqm_kernel<<<4096, 256, 0, stream>>>(bq, fh, fl, cbh, cbl, cb, cnorm, latent, idxf);
}